// Round 3
// baseline (149.818 us; speedup 1.0000x reference)
//
#include <hip/hip_runtime.h>

// Problem constants (match reference)
#define B_ROWS   256
#define L_COLS   65536
#define SLICES   4
#define THREADS  256
#define NBLOCKS  (B_ROWS * SLICES)          // 1024 blocks = 4 per CU
#define V_ROW    (L_COLS / 4)               // 16384 float4 per row
#define V_SLICE  (V_ROW / SLICES)           // 4096 float4 per slice
// per thread per input: V_SLICE/THREADS = 16 float4, as 4 batches of 4,
// 2-deep software pipeline so >=8 dwordx4 loads stay in flight.

__global__ __launch_bounds__(THREADS, 4)   // allow up to 128 VGPR: keep bufs live
void signal_loss_fused(const float4* __restrict__ pred,
                       const float4* __restrict__ trgt,
                       float* __restrict__ ws,
                       unsigned int* __restrict__ counter,
                       float* __restrict__ out)
{
    const int bid   = blockIdx.x;
    const int row   = bid >> 2;            // / SLICES
    const int slice = bid & (SLICES - 1);
    const size_t base = (size_t)row * V_ROW + (size_t)slice * V_SLICE + threadIdx.x;
    const float4* P = pred + base;
    const float4* T = trgt + base;

    float sp = 0.f, st = 0.f, spp = 0.f, stt = 0.f, spt = 0.f, sd2 = 0.f;

    float4 a0,a1,a2,a3, c0,c1,c2,c3;   // batch A: pred, trgt
    float4 b0,b1,b2,b3, d0,d1,d2,d3;   // batch B: pred, trgt

#define LOAD_A(bk) do { \
    a0 = P[((bk)*4+0)*THREADS]; a1 = P[((bk)*4+1)*THREADS]; \
    a2 = P[((bk)*4+2)*THREADS]; a3 = P[((bk)*4+3)*THREADS]; \
    c0 = T[((bk)*4+0)*THREADS]; c1 = T[((bk)*4+1)*THREADS]; \
    c2 = T[((bk)*4+2)*THREADS]; c3 = T[((bk)*4+3)*THREADS]; } while (0)

#define LOAD_B(bk) do { \
    b0 = P[((bk)*4+0)*THREADS]; b1 = P[((bk)*4+1)*THREADS]; \
    b2 = P[((bk)*4+2)*THREADS]; b3 = P[((bk)*4+3)*THREADS]; \
    d0 = T[((bk)*4+0)*THREADS]; d1 = T[((bk)*4+1)*THREADS]; \
    d2 = T[((bk)*4+2)*THREADS]; d3 = T[((bk)*4+3)*THREADS]; } while (0)

#define ACC1(p, t) do { \
    sp  += (p).x + (p).y + (p).z + (p).w; \
    st  += (t).x + (t).y + (t).z + (t).w; \
    spp += (p).x*(p).x + (p).y*(p).y + (p).z*(p).z + (p).w*(p).w; \
    stt += (t).x*(t).x + (t).y*(t).y + (t).z*(t).z + (t).w*(t).w; \
    spt += (p).x*(t).x + (p).y*(t).y + (p).z*(t).z + (p).w*(t).w; \
    { const float dx=(p).x-(t).x, dy=(p).y-(t).y, dz=(p).z-(t).z, dw=(p).w-(t).w; \
      sd2 += dx*dx + dy*dy + dz*dz + dw*dw; } } while (0)

#define ACC_A() do { ACC1(a0,c0); ACC1(a1,c1); ACC1(a2,c2); ACC1(a3,c3); } while (0)
#define ACC_B() do { ACC1(b0,d0); ACC1(b1,d1); ACC1(b2,d2); ACC1(b3,d3); } while (0)

    LOAD_A(0);          // 8 loads in flight
    LOAD_B(1);          // 16 in flight
    ACC_A();            // waits only on batch A
    LOAD_A(2);
    ACC_B();
    LOAD_B(3);
    ACC_A();
    ACC_B();

#undef LOAD_A
#undef LOAD_B
#undef ACC1
#undef ACC_A
#undef ACC_B

    // Wave-64 reduce
    #pragma unroll
    for (int off = 32; off >= 1; off >>= 1) {
        sp  += __shfl_down(sp,  off);
        st  += __shfl_down(st,  off);
        spp += __shfl_down(spp, off);
        stt += __shfl_down(stt, off);
        spt += __shfl_down(spt, off);
        sd2 += __shfl_down(sd2, off);
    }

    __shared__ float red[4][6];
    __shared__ unsigned int lastflag;
    const int lane = threadIdx.x & 63;
    const int wave = threadIdx.x >> 6;
    if (lane == 0) {
        red[wave][0] = sp;  red[wave][1] = st;  red[wave][2] = spp;
        red[wave][3] = stt; red[wave][4] = spt; red[wave][5] = sd2;
    }
    __syncthreads();
    if (threadIdx.x == 0) {
        float* dst = ws + (size_t)bid * 6;
        #pragma unroll
        for (int k = 0; k < 6; ++k) {
            const float v = red[0][k] + red[1][k] + red[2][k] + red[3][k];
            __hip_atomic_store(&dst[k], v, __ATOMIC_RELEASE, __HIP_MEMORY_SCOPE_AGENT);
        }
        const unsigned int old = __hip_atomic_fetch_add(
            counter, 1u, __ATOMIC_ACQ_REL, __HIP_MEMORY_SCOPE_AGENT);
        lastflag = (old == (unsigned int)(NBLOCKS - 1)) ? 1u : 0u;
    }
    __syncthreads();
    if (!lastflag) return;

    // ---- Last block: finalize. One thread per row. ----
    const int r = threadIdx.x;
    double s0=0.0, s1=0.0, s2=0.0, s3=0.0, s4=0.0, s5=0.0;
    #pragma unroll
    for (int sl = 0; sl < SLICES; ++sl) {
        const float* src = ws + ((size_t)r * SLICES + sl) * 6;
        s0 += (double)__hip_atomic_load(&src[0], __ATOMIC_RELAXED, __HIP_MEMORY_SCOPE_AGENT);
        s1 += (double)__hip_atomic_load(&src[1], __ATOMIC_RELAXED, __HIP_MEMORY_SCOPE_AGENT);
        s2 += (double)__hip_atomic_load(&src[2], __ATOMIC_RELAXED, __HIP_MEMORY_SCOPE_AGENT);
        s3 += (double)__hip_atomic_load(&src[3], __ATOMIC_RELAXED, __HIP_MEMORY_SCOPE_AGENT);
        s4 += (double)__hip_atomic_load(&src[4], __ATOMIC_RELAXED, __HIP_MEMORY_SCOPE_AGENT);
        s5 += (double)__hip_atomic_load(&src[5], __ATOMIC_RELAXED, __HIP_MEMORY_SCOPE_AGENT);
    }

    const double n = (double)L_COLS;
    const double num   = s4 - s0 * s1 / n;        // sum(xm*ym)
    const double den_t = s3 - s1 * s1 / n;        // sum(xm^2), xm from y_true
    const double den_p = s2 - s0 * s0 / n;        // sum(ym^2), ym from y_pred
    double den = sqrt(den_t * den_p);
    den = den > 1e-8 ? den : 1e-8;
    double romr = 1.0 - num / den;                // 1 - r for this row
    double sd   = s5;

    #pragma unroll
    for (int off = 32; off >= 1; off >>= 1) {
        romr += __shfl_down(romr, off);
        sd   += __shfl_down(sd,   off);
    }
    __shared__ double w0[4], w1[4];
    if (lane == 0) { w0[wave] = romr; w1[wave] = sd; }
    __syncthreads();
    if (threadIdx.x == 0) {
        const double corr = (w0[0] + w0[1] + w0[2] + w0[3]) / (double)B_ROWS;
        const double mse  = (w1[0] + w1[1] + w1[2] + w1[3])
                          / ((double)B_ROWS * (double)L_COLS);
        out[0] = (float)(0.7 * mse + 0.3 * corr);
    }
}

extern "C" void kernel_launch(void* const* d_in, const int* in_sizes, int n_in,
                              void* d_out, int out_size, void* d_ws, size_t ws_size,
                              hipStream_t stream) {
    const float4* pred = (const float4*)d_in[0];  // y_pred
    const float4* trgt = (const float4*)d_in[1];  // y_true
    float* ws  = (float*)d_ws;                    // NBLOCKS*6 floats = 24 KiB
    unsigned int* counter = (unsigned int*)((char*)d_ws + (size_t)NBLOCKS * 6 * sizeof(float));
    float* out = (float*)d_out;

    hipMemsetAsync(counter, 0, sizeof(unsigned int), stream);
    signal_loss_fused<<<NBLOCKS, THREADS, 0, stream>>>(pred, trgt, ws, counter, out);
}

// Round 4
// 28.882 us; speedup vs baseline: 5.1872x; 5.1872x over previous
//
#include <hip/hip_runtime.h>

// Problem constants (match reference)
#define B_ROWS   256
#define L_COLS   65536
#define SLICES   8
#define THREADS  256
#define NBLOCKS  (B_ROWS * SLICES)          // 2048 blocks = 8 per CU, all resident
#define V_ROW    (L_COLS / 4)               // 16384 float4 per row
#define V_SLICE  (V_ROW / SLICES)           // 2048 float4 per slice
// per thread per input: V_SLICE/THREADS = 8 float4, as 4 batches of 2,
// 2-deep ping-pong so ~8 dwordx4 loads stay in flight per lane.

__global__ __launch_bounds__(THREADS)
void signal_loss_partials(const float4* __restrict__ pred,
                          const float4* __restrict__ trgt,
                          float* __restrict__ ws)
{
    const int bid   = blockIdx.x;
    const int row   = bid >> 3;             // / SLICES
    const int slice = bid & (SLICES - 1);
    const size_t base = (size_t)row * V_ROW + (size_t)slice * V_SLICE + threadIdx.x;
    const float4* P = pred + base;
    const float4* T = trgt + base;

    float sp = 0.f, st = 0.f, spp = 0.f, stt = 0.f, spt = 0.f, sd2 = 0.f;

    float4 a0, a1, c0, c1;   // batch A: 2 pred + 2 trgt
    float4 b0, b1, d0, d1;   // batch B: 2 pred + 2 trgt

#define LOAD_A(bk) do { \
    a0 = P[((bk)*2+0)*THREADS]; a1 = P[((bk)*2+1)*THREADS]; \
    c0 = T[((bk)*2+0)*THREADS]; c1 = T[((bk)*2+1)*THREADS]; } while (0)
#define LOAD_B(bk) do { \
    b0 = P[((bk)*2+0)*THREADS]; b1 = P[((bk)*2+1)*THREADS]; \
    d0 = T[((bk)*2+0)*THREADS]; d1 = T[((bk)*2+1)*THREADS]; } while (0)

#define ACC1(p, t) do { \
    sp  += (p).x + (p).y + (p).z + (p).w; \
    st  += (t).x + (t).y + (t).z + (t).w; \
    spp += (p).x*(p).x + (p).y*(p).y + (p).z*(p).z + (p).w*(p).w; \
    stt += (t).x*(t).x + (t).y*(t).y + (t).z*(t).z + (t).w*(t).w; \
    spt += (p).x*(t).x + (p).y*(t).y + (p).z*(t).z + (p).w*(t).w; \
    { const float dx=(p).x-(t).x, dy=(p).y-(t).y, dz=(p).z-(t).z, dw=(p).w-(t).w; \
      sd2 += dx*dx + dy*dy + dz*dz + dw*dw; } } while (0)

    LOAD_A(0);                       // 4 loads in flight
    LOAD_B(1);                       // 8 in flight
    ACC1(a0, c0); ACC1(a1, c1);      // consume A (waits only on A)
    LOAD_A(2);
    ACC1(b0, d0); ACC1(b1, d1);      // consume B
    LOAD_B(3);
    ACC1(a0, c0); ACC1(a1, c1);
    ACC1(b0, d0); ACC1(b1, d1);

#undef LOAD_A
#undef LOAD_B
#undef ACC1

    // Wave-64 reduce via shfl_down
    #pragma unroll
    for (int off = 32; off >= 1; off >>= 1) {
        sp  += __shfl_down(sp,  off);
        st  += __shfl_down(st,  off);
        spp += __shfl_down(spp, off);
        stt += __shfl_down(stt, off);
        spt += __shfl_down(spt, off);
        sd2 += __shfl_down(sd2, off);
    }

    __shared__ float red[4][6];
    const int lane = threadIdx.x & 63;
    const int wave = threadIdx.x >> 6;
    if (lane == 0) {
        red[wave][0] = sp;  red[wave][1] = st;  red[wave][2] = spp;
        red[wave][3] = stt; red[wave][4] = spt; red[wave][5] = sd2;
    }
    __syncthreads();
    if (threadIdx.x == 0) {
        // Records padded to 8 floats so finalize can read 2×float4 per record.
        float* dst = ws + (size_t)bid * 8;
        #pragma unroll
        for (int k = 0; k < 6; ++k)
            dst[k] = red[0][k] + red[1][k] + red[2][k] + red[3][k];
        dst[6] = 0.f; dst[7] = 0.f;
    }
}

__global__ __launch_bounds__(B_ROWS)
void signal_loss_finalize(const float4* __restrict__ ws4,
                          float* __restrict__ out)
{
    const int row = threadIdx.x;  // one thread per row, 256 threads

    // Issue all 16 float4 loads up front (independent, one latency shot).
    float4 lo[SLICES], hi[SLICES];
    #pragma unroll
    for (int sl = 0; sl < SLICES; ++sl) {
        const size_t rec = ((size_t)row * SLICES + sl) * 2;  // 2 float4 per record
        lo[sl] = ws4[rec + 0];
        hi[sl] = ws4[rec + 1];
    }

    double s0=0.0, s1=0.0, s2=0.0, s3=0.0, s4=0.0, s5=0.0;
    #pragma unroll
    for (int sl = 0; sl < SLICES; ++sl) {
        s0 += (double)lo[sl].x;  // sum p
        s1 += (double)lo[sl].y;  // sum t
        s2 += (double)lo[sl].z;  // sum p^2
        s3 += (double)lo[sl].w;  // sum t^2
        s4 += (double)hi[sl].x;  // sum p*t
        s5 += (double)hi[sl].y;  // sum (p-t)^2
    }

    const double n = (double)L_COLS;
    const double num   = s4 - s0 * s1 / n;        // sum(xm*ym)
    const double den_t = s3 - s1 * s1 / n;        // sum(xm^2), xm from y_true
    const double den_p = s2 - s0 * s0 / n;        // sum(ym^2), ym from y_pred
    double den = sqrt(den_t * den_p);
    den = den > 1e-8 ? den : 1e-8;
    double romr = 1.0 - num / den;                // 1 - r for this row
    double sd   = s5;

    #pragma unroll
    for (int off = 32; off >= 1; off >>= 1) {
        romr += __shfl_down(romr, off);
        sd   += __shfl_down(sd,   off);
    }
    __shared__ double w0[4], w1[4];
    const int lane = threadIdx.x & 63;
    const int wave = threadIdx.x >> 6;
    if (lane == 0) { w0[wave] = romr; w1[wave] = sd; }
    __syncthreads();
    if (threadIdx.x == 0) {
        const double corr = (w0[0] + w0[1] + w0[2] + w0[3]) / (double)B_ROWS;
        const double mse  = (w1[0] + w1[1] + w1[2] + w1[3])
                          / ((double)B_ROWS * (double)L_COLS);
        out[0] = (float)(0.7 * mse + 0.3 * corr);
    }
}

extern "C" void kernel_launch(void* const* d_in, const int* in_sizes, int n_in,
                              void* d_out, int out_size, void* d_ws, size_t ws_size,
                              hipStream_t stream) {
    const float4* pred = (const float4*)d_in[0];  // y_pred
    const float4* trgt = (const float4*)d_in[1];  // y_true
    float* ws  = (float*)d_ws;                    // NBLOCKS*8 floats = 64 KiB partials
    float* out = (float*)d_out;

    signal_loss_partials<<<NBLOCKS, THREADS, 0, stream>>>(pred, trgt, ws);
    signal_loss_finalize<<<1, B_ROWS, 0, stream>>>((const float4*)ws, out);
}